// Round 1
// baseline (1131.730 us; speedup 1.0000x reference)
//
#include <hip/hip_runtime.h>
#include <stdint.h>
#include <stddef.h>

// ---------------------------------------------------------------------------
// Connectivity3D: PointNet (6->64->128->256, BN affine folded, max-pool) ->
// object_embedding -> 2x GCN -> edge MLP -> tanh -> [512,16,16] scatter.
//
// Algebraic collapse: dense intra-object edges => deg=16, norm=1/16 for all
// edges => GCN layer output = (per-object sum of xw)/16 + b, identical for
// all 16 parts of an object. Hence the edge score is ONE scalar per object,
// and only fsum[obj] = sum_parts feat[node] is needed downstream.
// ---------------------------------------------------------------------------

typedef short bf16x8 __attribute__((ext_vector_type(8)));
typedef float f32x4  __attribute__((ext_vector_type(4)));

// workspace byte offsets (all 16B aligned)
#define WT1_OFF   0u        // bf16 [64][32]   (W1*g1)^T, k-padded 6->32 with zeros
#define WT2_OFF   4096u     // bf16 [128][64]  (W2*g2)^T
#define WT3_OFF   20480u    // bf16 [256][128] (W3*g3)^T
#define B1F_OFF   86016u    // f32 [64]   b1*g1+bt1
#define B2F_OFF   86272u    // f32 [128]
#define B3F_OFF   86784u    // f32 [256]
#define FSUM_OFF  87808u    // f32 [512][256]
#define WC1S_OFF  612096u   // f32 [256][256] Wc1[0:256]+Wc1[256:512]

__device__ __forceinline__ unsigned short f2bf(float f) {
  union { float f; unsigned u; } v; v.f = f;
  unsigned r = v.u + 0x7fffu + ((v.u >> 16) & 1u);   // round-to-nearest-even
  return (unsigned short)(r >> 16);
}

// ---------------------------------------------------------------------------
__global__ void prep_kernel(
    const float* __restrict__ W1, const float* __restrict__ b1,
    const float* __restrict__ g1, const float* __restrict__ bt1,
    const float* __restrict__ W2, const float* __restrict__ b2,
    const float* __restrict__ g2, const float* __restrict__ bt2,
    const float* __restrict__ W3, const float* __restrict__ b3,
    const float* __restrict__ g3, const float* __restrict__ bt3,
    const float* __restrict__ Wc1, unsigned char* __restrict__ ws)
{
  unsigned short* wt1 = (unsigned short*)(ws + WT1_OFF);
  unsigned short* wt2 = (unsigned short*)(ws + WT2_OFF);
  unsigned short* wt3 = (unsigned short*)(ws + WT3_OFF);
  float* b1f  = (float*)(ws + B1F_OFF);
  float* b2f  = (float*)(ws + B2F_OFF);
  float* b3f  = (float*)(ws + B3F_OFF);
  float* wc1s = (float*)(ws + WC1S_OFF);

  int i = blockIdx.x * 256 + threadIdx.x;
  if (i < 2048) { int o = i >> 5, c = i & 31;                 // wt1[o][c]
    wt1[i] = f2bf(c < 6 ? W1[c*64 + o] * g1[o] : 0.f); return; }
  i -= 2048;
  if (i < 8192) { int o = i >> 6, c = i & 63;                 // wt2[o][c]
    wt2[i] = f2bf(W2[c*128 + o] * g2[o]); return; }
  i -= 8192;
  if (i < 32768) { int o = i >> 7, c = i & 127;               // wt3[o][c]
    wt3[i] = f2bf(W3[c*256 + o] * g3[o]); return; }
  i -= 32768;
  if (i < 64)  { b1f[i] = b1[i]*g1[i] + bt1[i]; return; }
  i -= 64;
  if (i < 128) { b2f[i] = b2[i]*g2[i] + bt2[i]; return; }
  i -= 128;
  if (i < 256) { b3f[i] = b3[i]*g3[i] + bt3[i]; return; }
  i -= 256;
  if (i < 65536) { wc1s[i] = Wc1[i] + Wc1[i + 65536]; }
}

// ---------------------------------------------------------------------------
// One block per object (512 blocks x 256 thr = 4 waves). Chunk = 128 points.
// LDS (bf16, padded rows for bank balance): x[128][40], h1[128][72], h2[128][136]
#define LDSX  0
#define LDSH1 5120
#define LDSH2 14336

__global__ __launch_bounds__(256, 2) void pointnet_kernel(
    const float* __restrict__ pcls, const unsigned char* __restrict__ ws,
    float* __restrict__ fsum)
{
  __shared__ unsigned short lds[31744];   // 62 KB -> 2 blocks/CU

  const unsigned short* wt1 = (const unsigned short*)(ws + WT1_OFF);
  const unsigned short* wt2 = (const unsigned short*)(ws + WT2_OFF);
  const unsigned short* wt3 = (const unsigned short*)(ws + WT3_OFF);
  const float* b1f = (const float*)(ws + B1F_OFF);
  const float* b2f = (const float*)(ws + B2F_OFF);
  const float* b3f = (const float*)(ws + B3F_OFF);

  const int tid  = threadIdx.x;
  const int w    = tid >> 6;        // wave 0..3
  const int lane = tid & 63;
  const int l15  = lane & 15;
  const int q    = lane >> 4;       // quad 0..3
  const int obj  = blockIdx.x;

  // --- B fragments (transposed weights), resident in VGPRs for whole block
  bf16x8 bf1 = *(const bf16x8*)(wt1 + (16*w + l15)*32 + q*8);
  bf16x8 bf2[2][2], bf3[4][4];
#pragma unroll
  for (int nt = 0; nt < 2; ++nt)
#pragma unroll
    for (int k = 0; k < 2; ++k)
      bf2[nt][k] = *(const bf16x8*)(wt2 + (32*w + nt*16 + l15)*64 + k*32 + q*8);
#pragma unroll
  for (int nt = 0; nt < 4; ++nt)
#pragma unroll
    for (int k = 0; k < 4; ++k)
      bf3[nt][k] = *(const bf16x8*)(wt3 + (64*w + nt*16 + l15)*128 + k*32 + q*8);

  const float bias1 = b1f[16*w + l15];
  float bias2[2], bias3[4];
#pragma unroll
  for (int nt = 0; nt < 2; ++nt) bias2[nt] = b2f[32*w + nt*16 + l15];
#pragma unroll
  for (int nt = 0; nt < 4; ++nt) bias3[nt] = b3f[64*w + nt*16 + l15];

  // per-thread staging slots: 768 floats/chunk = 3 per thread
  int soff[3];
#pragma unroll
  for (int j = 0; j < 3; ++j) {
    int i = tid + 256*j; int p = i / 6; int c = i - 6*p;
    soff[j] = LDSX + p*40 + c;
  }

  // zero x buffer once (cols >=6 stay zero forever = K padding)
  for (int i = tid; i < 5120; i += 256) lds[LDSX + i] = 0;
  __syncthreads();

  const float* pbase = pcls + (size_t)obj * 49152;   // 8192 pts * 6
#pragma unroll
  for (int j = 0; j < 3; ++j)
    lds[soff[j]] = f2bf(pbase[tid + 256*j]);

  f32x4 macc[4]; float sacc[4] = {0.f, 0.f, 0.f, 0.f};
#pragma unroll
  for (int nt = 0; nt < 4; ++nt) macc[nt] = (f32x4){-3e38f, -3e38f, -3e38f, -3e38f};

  for (int cg = 0; cg < 64; ++cg) {
    __syncthreads();                       // x(cg) visible, h buffers free
    // ---- layer 1: x[128x32] @ W1t -> h1[128x64], relu (wave w: ch 16w..16w+15)
#pragma unroll
    for (int mt = 0; mt < 8; ++mt) {
      bf16x8 a = *(const bf16x8*)(&lds[LDSX + (mt*16 + l15)*40 + q*8]);
      f32x4 d = {bias1, bias1, bias1, bias1};
      d = __builtin_amdgcn_mfma_f32_16x16x32_bf16(a, bf1, d, 0, 0, 0);
#pragma unroll
      for (int r = 0; r < 4; ++r)
        lds[LDSH1 + (mt*16 + q*4 + r)*72 + 16*w + l15] = f2bf(fmaxf(d[r], 0.f));
    }
    __syncthreads();
    // ---- layer 2: h1 @ W2t -> h2[128x128], relu (wave w: ch 32w..32w+31)
#pragma unroll
    for (int mt = 0; mt < 8; ++mt) {
      bf16x8 a0 = *(const bf16x8*)(&lds[LDSH1 + (mt*16 + l15)*72 + q*8]);
      bf16x8 a1 = *(const bf16x8*)(&lds[LDSH1 + (mt*16 + l15)*72 + 32 + q*8]);
#pragma unroll
      for (int nt = 0; nt < 2; ++nt) {
        f32x4 d = {bias2[nt], bias2[nt], bias2[nt], bias2[nt]};
        d = __builtin_amdgcn_mfma_f32_16x16x32_bf16(a0, bf2[nt][0], d, 0, 0, 0);
        d = __builtin_amdgcn_mfma_f32_16x16x32_bf16(a1, bf2[nt][1], d, 0, 0, 0);
#pragma unroll
        for (int r = 0; r < 4; ++r)
          lds[LDSH2 + (mt*16 + q*4 + r)*136 + 32*w + nt*16 + l15] = f2bf(fmaxf(d[r], 0.f));
      }
    }
    __syncthreads();
    // prefetch next chunk's points into regs (hidden under layer-3 MFMAs)
    float pf[3];
    const int havenext = (cg < 63);
    if (havenext) {
#pragma unroll
      for (int j = 0; j < 3; ++j) pf[j] = pbase[(cg + 1)*768 + tid + 256*j];
    }
    // ---- layer 3: h2 @ W3t + b3 -> max-accumulate (wave w: ch 64w..64w+63)
#pragma unroll
    for (int mt = 0; mt < 8; ++mt) {
      bf16x8 a[4];
#pragma unroll
      for (int k = 0; k < 4; ++k)
        a[k] = *(const bf16x8*)(&lds[LDSH2 + (mt*16 + l15)*136 + k*32 + q*8]);
#pragma unroll
      for (int nt = 0; nt < 4; ++nt) {
        f32x4 d = {bias3[nt], bias3[nt], bias3[nt], bias3[nt]};
#pragma unroll
        for (int k = 0; k < 4; ++k)
          d = __builtin_amdgcn_mfma_f32_16x16x32_bf16(a[k], bf3[nt][k], d, 0, 0, 0);
#pragma unroll
        for (int r = 0; r < 4; ++r)
          macc[nt][r] = fmaxf(macc[nt][r], d[r]);
      }
    }
    __syncthreads();                       // h2 reads done; safe to restage x
    if (havenext) {
#pragma unroll
      for (int j = 0; j < 3; ++j) lds[soff[j]] = f2bf(pf[j]);
    }
    // part boundary (every 4 chunks = 512 points): reduce max, add to sum
    if ((cg & 3) == 3) {
#pragma unroll
      for (int nt = 0; nt < 4; ++nt) {
        float v = fmaxf(fmaxf(macc[nt][0], macc[nt][1]), fmaxf(macc[nt][2], macc[nt][3]));
        v = fmaxf(v, __shfl_xor(v, 16));
        v = fmaxf(v, __shfl_xor(v, 32));
        sacc[nt] += v;
        macc[nt] = (f32x4){-3e38f, -3e38f, -3e38f, -3e38f};
      }
    }
  }
  // write fsum: lane (q,l15) writes channel 64w + q*16 + l15 using sacc[q]
  float val = (q == 0) ? sacc[0] : (q == 1) ? sacc[1] : (q == 2) ? sacc[2] : sacc[3];
  fsum[obj*256 + w*64 + lane] = val;
}

// ---------------------------------------------------------------------------
// Per-object: esum=fsum@We+16be; x1=relu(esum@Wg1/16+bg1); x2=x1@Wg2+bg2;
// h=relu(x2@Wc1s+bc1); h2=relu(h@Wc2+bc2); c=tanh(h2.Wc3+bc3); fill 16x16.
__global__ __launch_bounds__(256) void objmlp_kernel(
    const float* __restrict__ We,  const float* __restrict__ be,
    const float* __restrict__ Wg1, const float* __restrict__ bg1,
    const float* __restrict__ Wg2, const float* __restrict__ bg2,
    const float* __restrict__ bc1,
    const float* __restrict__ Wc2, const float* __restrict__ bc2,
    const float* __restrict__ Wc3, const float* __restrict__ bc3,
    const unsigned char* __restrict__ ws, float* __restrict__ out)
{
  const float* fsum = (const float*)(ws + FSUM_OFF);
  const float* Wc1s = (const float*)(ws + WC1S_OFF);
  __shared__ float bufA[256], bufB[256], red[4], cval_s;
  const int t = threadIdx.x, obj = blockIdx.x;

  bufA[t] = fsum[obj*256 + t];
  __syncthreads();
  float acc = 0.f;
#pragma unroll 8
  for (int c = 0; c < 256; ++c) acc += bufA[c] * We[c*256 + t];
  bufB[t] = acc + 16.f * be[t];
  __syncthreads();
  acc = 0.f;
#pragma unroll 8
  for (int c = 0; c < 256; ++c) acc += bufB[c] * Wg1[c*256 + t];
  bufA[t] = fmaxf(acc * 0.0625f + bg1[t], 0.f);
  __syncthreads();
  acc = 0.f;
#pragma unroll 8
  for (int c = 0; c < 256; ++c) acc += bufA[c] * Wg2[c*256 + t];
  bufB[t] = acc + bg2[t];
  __syncthreads();
  acc = 0.f;
#pragma unroll 8
  for (int c = 0; c < 256; ++c) acc += bufB[c] * Wc1s[c*256 + t];
  bufA[t] = fmaxf(acc + bc1[t], 0.f);
  __syncthreads();
  acc = 0.f;
#pragma unroll 8
  for (int c = 0; c < 256; ++c) acc += bufA[c] * Wc2[c*256 + t];
  float h2v = fmaxf(acc + bc2[t], 0.f);

  float part = h2v * Wc3[t];
#pragma unroll
  for (int off = 1; off < 64; off <<= 1) part += __shfl_xor(part, off);
  if ((t & 63) == 0) red[t >> 6] = part;
  __syncthreads();
  if (t == 0) cval_s = tanhf(red[0] + red[1] + red[2] + red[3] + bc3[0]);
  __syncthreads();
  const float cv = cval_s;
  out[obj*256 + t] = ((t >> 4) == (t & 15)) ? 0.f : cv;
}

// ---------------------------------------------------------------------------
extern "C" void kernel_launch(void* const* d_in, const int* in_sizes, int n_in,
                              void* d_out, int out_size, void* d_ws, size_t ws_size,
                              hipStream_t stream) {
  const float* pcls = (const float*)d_in[0];
  const float* W1 = (const float*)d_in[1];  const float* b1 = (const float*)d_in[2];
  const float* g1 = (const float*)d_in[3];  const float* bt1 = (const float*)d_in[4];
  const float* W2 = (const float*)d_in[5];  const float* b2 = (const float*)d_in[6];
  const float* g2 = (const float*)d_in[7];  const float* bt2 = (const float*)d_in[8];
  const float* W3 = (const float*)d_in[9];  const float* b3 = (const float*)d_in[10];
  const float* g3 = (const float*)d_in[11]; const float* bt3 = (const float*)d_in[12];
  const float* We = (const float*)d_in[13]; const float* be = (const float*)d_in[14];
  const float* Wg1 = (const float*)d_in[15]; const float* bg1 = (const float*)d_in[16];
  const float* Wg2 = (const float*)d_in[17]; const float* bg2 = (const float*)d_in[18];
  const float* Wc1 = (const float*)d_in[19]; const float* bc1 = (const float*)d_in[20];
  const float* Wc2 = (const float*)d_in[21]; const float* bc2 = (const float*)d_in[22];
  const float* Wc3 = (const float*)d_in[23]; const float* bc3 = (const float*)d_in[24];
  unsigned char* ws = (unsigned char*)d_ws;
  float* out = (float*)d_out;

  prep_kernel<<<426, 256, 0, stream>>>(W1, b1, g1, bt1, W2, b2, g2, bt2,
                                       W3, b3, g3, bt3, Wc1, ws);
  pointnet_kernel<<<512, 256, 0, stream>>>(pcls, ws, (float*)(ws + FSUM_OFF));
  objmlp_kernel<<<512, 256, 0, stream>>>(We, be, Wg1, bg1, Wg2, bg2, bc1,
                                         Wc2, bc2, Wc3, bc3, ws, out);
}

// Round 2
// 558.809 us; speedup vs baseline: 2.0253x; 2.0253x over previous
//
#include <hip/hip_runtime.h>
#include <stdint.h>
#include <stddef.h>

// ---------------------------------------------------------------------------
// Connectivity3D: PointNet (6->64->128->256, BN folded, max-pool) ->
// object_embedding -> 2x GCN -> edge MLP -> tanh -> [512,16,16].
//
// Algebraic collapse: dense intra-object edges => deg=16 for every node =>
// GCN output = (per-object mean of xw) + b, identical for all 16 parts =>
// ONE edge score per object; only fsum[obj] = sum_parts feat is needed.
//
// R1 changes vs R0 (which spilled ~950 MB of scratch to HBM):
//  - amdgpu_waves_per_eu(2,2): pin 2 waves/EU -> 256-VGPR budget, no spill.
//  - MFMA orientation flipped: weights=A (register-resident fragments),
//    activations=B. D rows = channels -> packed b64 LDS stores; next layer
//    reads b128. Bias init via f32x4 vector load.
//  - 3 barriers/iter; point staging overlapped with layer-2 phase.
// ---------------------------------------------------------------------------

typedef short bf16x8 __attribute__((ext_vector_type(8)));
typedef short bf16x4 __attribute__((ext_vector_type(4)));
typedef float f32x4  __attribute__((ext_vector_type(4)));

// workspace byte offsets (all 16B aligned)
#define WT1_OFF   0u        // bf16 [64][32]   (W1*g1)^T, k-padded 6->32 with zeros
#define WT2_OFF   4096u     // bf16 [128][64]  (W2*g2)^T
#define WT3_OFF   20480u    // bf16 [256][128] (W3*g3)^T
#define B1F_OFF   86016u    // f32 [64]   b1*g1+bt1
#define B2F_OFF   86272u    // f32 [128]
#define B3F_OFF   86784u    // f32 [256]
#define FSUM_OFF  87808u    // f32 [512][256]
#define WC1S_OFF  612096u   // f32 [256][256] Wc1[0:256]+Wc1[256:512]

__device__ __forceinline__ unsigned short f2bf(float f) {
  union { float f; unsigned u; } v; v.f = f;
  unsigned r = v.u + 0x7fffu + ((v.u >> 16) & 1u);   // round-to-nearest-even
  return (unsigned short)(r >> 16);
}

__device__ __forceinline__ bf16x4 pack_relu4(f32x4 d) {
  bf16x4 o;
  o.x = (short)f2bf(fmaxf(d.x, 0.f));
  o.y = (short)f2bf(fmaxf(d.y, 0.f));
  o.z = (short)f2bf(fmaxf(d.z, 0.f));
  o.w = (short)f2bf(fmaxf(d.w, 0.f));
  return o;
}

// ---------------------------------------------------------------------------
__global__ void prep_kernel(
    const float* __restrict__ W1, const float* __restrict__ b1,
    const float* __restrict__ g1, const float* __restrict__ bt1,
    const float* __restrict__ W2, const float* __restrict__ b2,
    const float* __restrict__ g2, const float* __restrict__ bt2,
    const float* __restrict__ W3, const float* __restrict__ b3,
    const float* __restrict__ g3, const float* __restrict__ bt3,
    const float* __restrict__ Wc1, unsigned char* __restrict__ ws)
{
  unsigned short* wt1 = (unsigned short*)(ws + WT1_OFF);
  unsigned short* wt2 = (unsigned short*)(ws + WT2_OFF);
  unsigned short* wt3 = (unsigned short*)(ws + WT3_OFF);
  float* b1f  = (float*)(ws + B1F_OFF);
  float* b2f  = (float*)(ws + B2F_OFF);
  float* b3f  = (float*)(ws + B3F_OFF);
  float* wc1s = (float*)(ws + WC1S_OFF);

  int i = blockIdx.x * 256 + threadIdx.x;
  if (i < 2048) { int o = i >> 5, c = i & 31;                 // wt1[o][c]
    wt1[i] = f2bf(c < 6 ? W1[c*64 + o] * g1[o] : 0.f); return; }
  i -= 2048;
  if (i < 8192) { int o = i >> 6, c = i & 63;                 // wt2[o][c]
    wt2[i] = f2bf(W2[c*128 + o] * g2[o]); return; }
  i -= 8192;
  if (i < 32768) { int o = i >> 7, c = i & 127;               // wt3[o][c]
    wt3[i] = f2bf(W3[c*256 + o] * g3[o]); return; }
  i -= 32768;
  if (i < 64)  { b1f[i] = b1[i]*g1[i] + bt1[i]; return; }
  i -= 64;
  if (i < 128) { b2f[i] = b2[i]*g2[i] + bt2[i]; return; }
  i -= 128;
  if (i < 256) { b3f[i] = b3[i]*g3[i] + bt3[i]; return; }
  i -= 256;
  if (i < 65536) { wc1s[i] = Wc1[i] + Wc1[i + 65536]; }
}

// ---------------------------------------------------------------------------
// One block per object (512 blocks x 256 thr = 4 waves). Chunk = 128 points.
// LDS layout [pt][ch], bf16, row strides odd multiples of 8 shorts:
//   x[128][40], h1[128][72], h2[128][136]
#define LDSX  0
#define LDSH1 5120
#define LDSH2 14336

__global__ __launch_bounds__(256)
__attribute__((amdgpu_waves_per_eu(2, 2)))
void pointnet_kernel(
    const float* __restrict__ pcls, const unsigned char* __restrict__ ws,
    float* __restrict__ fsum)
{
  __shared__ __align__(16) unsigned short lds[31744];   // 62 KB -> 2 blocks/CU

  const unsigned short* wt1 = (const unsigned short*)(ws + WT1_OFF);
  const unsigned short* wt2 = (const unsigned short*)(ws + WT2_OFF);
  const unsigned short* wt3 = (const unsigned short*)(ws + WT3_OFF);
  const float* b1f = (const float*)(ws + B1F_OFF);
  const float* b2f = (const float*)(ws + B2F_OFF);
  const float* b3f = (const float*)(ws + B3F_OFF);

  const int tid  = threadIdx.x;
  const int w    = tid >> 6;        // wave 0..3 -> output-channel slice
  const int lane = tid & 63;
  const int l15  = lane & 15;
  const int q    = lane >> 4;       // quad 0..3
  const int obj  = blockIdx.x;

  // --- Weight A-fragments, register-resident for the whole block.
  // A[m = l15][k = q*8+j]; wave w owns ch slice {16w | 32w..+31 | 64w..+63}.
  bf16x8 af1 = *(const bf16x8*)(wt1 + (16*w + l15)*32 + q*8);
  bf16x8 af2[2][2], af3[4][4];
#pragma unroll
  for (int nt = 0; nt < 2; ++nt)
#pragma unroll
    for (int kf = 0; kf < 2; ++kf)
      af2[nt][kf] = *(const bf16x8*)(wt2 + (32*w + nt*16 + l15)*64 + kf*32 + q*8);
#pragma unroll
  for (int nt = 0; nt < 4; ++nt)
#pragma unroll
    for (int kf = 0; kf < 4; ++kf)
      af3[nt][kf] = *(const bf16x8*)(wt3 + (64*w + nt*16 + l15)*128 + kf*32 + q*8);

  // D rows = ch = base + q*4 + r  -> bias as f32x4 vector loads
  const f32x4 bias1 = *(const f32x4*)(b1f + 16*w + q*4);
  f32x4 bias2[2], bias3[4];
#pragma unroll
  for (int nt = 0; nt < 2; ++nt) bias2[nt] = *(const f32x4*)(b2f + 32*w + nt*16 + q*4);
#pragma unroll
  for (int nt = 0; nt < 4; ++nt) bias3[nt] = *(const f32x4*)(b3f + 64*w + nt*16 + q*4);

  // point staging: 768 floats/chunk = 3 per thread, layout x[pt][40]
  int soff[3];
#pragma unroll
  for (int j = 0; j < 3; ++j) {
    int i = tid + 256*j; int p = i / 6; int c = i - 6*p;
    soff[j] = LDSX + p*40 + c;
  }

  // zero x buffer once (cols 6..31 stay zero = K padding)
  for (int i = tid; i < 5120; i += 256) lds[LDSX + i] = 0;
  __syncthreads();

  const float* pbase = pcls + (size_t)obj * 49152;   // 8192 pts * 6 floats
#pragma unroll
  for (int j = 0; j < 3; ++j)
    lds[soff[j]] = f2bf(pbase[tid + 256*j]);
  __syncthreads();

  f32x4 macc[4];
  float sacc[4][4];
#pragma unroll
  for (int nt = 0; nt < 4; ++nt) {
    macc[nt] = (f32x4){-3e38f, -3e38f, -3e38f, -3e38f};
#pragma unroll
    for (int r = 0; r < 4; ++r) sacc[nt][r] = 0.f;
  }

  for (int cg = 0; cg < 64; ++cg) {
    // ---- layer 1: 6(->32 pad) -> 64, relu.  D[ch 16w+q*4+r][pt]
#pragma unroll
    for (int pt = 0; pt < 8; ++pt) {
      bf16x8 b = *(const bf16x8*)(&lds[LDSX + (pt*16 + l15)*40 + q*8]);
      f32x4 d = bias1;
      d = __builtin_amdgcn_mfma_f32_16x16x32_bf16(af1, b, d, 0, 0, 0);
      *(bf16x4*)(&lds[LDSH1 + (pt*16 + l15)*72 + 16*w + q*4]) = pack_relu4(d);
    }
    __syncthreads();                 // x reads + h1 writes complete

    // prefetch next chunk's points (global latency hidden under layer 2)
    float pf[3];
    const int havenext = (cg < 63);
    if (havenext) {
#pragma unroll
      for (int j = 0; j < 3; ++j) pf[j] = pbase[(cg + 1)*768 + tid + 256*j];
    }

    // ---- layer 2: 64 -> 128, relu
#pragma unroll
    for (int pt = 0; pt < 8; ++pt) {
      bf16x8 b0 = *(const bf16x8*)(&lds[LDSH1 + (pt*16 + l15)*72 + q*8]);
      bf16x8 b1v = *(const bf16x8*)(&lds[LDSH1 + (pt*16 + l15)*72 + 32 + q*8]);
#pragma unroll
      for (int nt = 0; nt < 2; ++nt) {
        f32x4 d = bias2[nt];
        d = __builtin_amdgcn_mfma_f32_16x16x32_bf16(af2[nt][0], b0, d, 0, 0, 0);
        d = __builtin_amdgcn_mfma_f32_16x16x32_bf16(af2[nt][1], b1v, d, 0, 0, 0);
        *(bf16x4*)(&lds[LDSH2 + (pt*16 + l15)*136 + 32*w + nt*16 + q*4]) = pack_relu4(d);
      }
    }
    // stage prefetched points into x (for cg+1; x reads finished at sync above)
    if (havenext) {
#pragma unroll
      for (int j = 0; j < 3; ++j) lds[soff[j]] = f2bf(pf[j]);
    }
    __syncthreads();                 // h1 reads + h2/x writes complete

    // ---- layer 3: 128 -> 256, max-accumulate (no LDS write)
#pragma unroll
    for (int pt = 0; pt < 8; ++pt) {
      bf16x8 b[4];
#pragma unroll
      for (int kf = 0; kf < 4; ++kf)
        b[kf] = *(const bf16x8*)(&lds[LDSH2 + (pt*16 + l15)*136 + kf*32 + q*8]);
#pragma unroll
      for (int nt = 0; nt < 4; ++nt) {
        f32x4 d = bias3[nt];
#pragma unroll
        for (int kf = 0; kf < 4; ++kf)
          d = __builtin_amdgcn_mfma_f32_16x16x32_bf16(af3[nt][kf], b[kf], d, 0, 0, 0);
#pragma unroll
        for (int r = 0; r < 4; ++r)
          macc[nt][r] = fmaxf(macc[nt][r], d[r]);
      }
    }
    // part boundary (512 points = 4 chunks): reduce max over the 16 pt-lanes
    if ((cg & 3) == 3) {
#pragma unroll
      for (int nt = 0; nt < 4; ++nt) {
#pragma unroll
        for (int r = 0; r < 4; ++r) {
          float v = macc[nt][r];
          v = fmaxf(v, __shfl_xor(v, 1));
          v = fmaxf(v, __shfl_xor(v, 2));
          v = fmaxf(v, __shfl_xor(v, 4));
          v = fmaxf(v, __shfl_xor(v, 8));
          sacc[nt][r] += v;
        }
        macc[nt] = (f32x4){-3e38f, -3e38f, -3e38f, -3e38f};
      }
    }
    __syncthreads();                 // h2 reads complete; x(cg+1) visible
  }

  // write fsum: ch = 64w + nt*16 + q*4 + r (value replicated across l15)
#pragma unroll
  for (int r = 0; r < 4; ++r) {
    if (l15 == r) {
#pragma unroll
      for (int nt = 0; nt < 4; ++nt)
        fsum[obj*256 + 64*w + nt*16 + q*4 + r] = sacc[nt][r];
    }
  }
}

// ---------------------------------------------------------------------------
// Per-object: esum=fsum@We+16be; x1=relu(esum@Wg1/16+bg1); x2=x1@Wg2+bg2;
// h=relu(x2@Wc1s+bc1); h2=relu(h@Wc2+bc2); c=tanh(h2.Wc3+bc3); fill 16x16.
__global__ __launch_bounds__(256) void objmlp_kernel(
    const float* __restrict__ We,  const float* __restrict__ be,
    const float* __restrict__ Wg1, const float* __restrict__ bg1,
    const float* __restrict__ Wg2, const float* __restrict__ bg2,
    const float* __restrict__ bc1,
    const float* __restrict__ Wc2, const float* __restrict__ bc2,
    const float* __restrict__ Wc3, const float* __restrict__ bc3,
    const unsigned char* __restrict__ ws, float* __restrict__ out)
{
  const float* fsum = (const float*)(ws + FSUM_OFF);
  const float* Wc1s = (const float*)(ws + WC1S_OFF);
  __shared__ float bufA[256], bufB[256], red[4], cval_s;
  const int t = threadIdx.x, obj = blockIdx.x;

  bufA[t] = fsum[obj*256 + t];
  __syncthreads();
  float acc = 0.f;
#pragma unroll 8
  for (int c = 0; c < 256; ++c) acc += bufA[c] * We[c*256 + t];
  bufB[t] = acc + 16.f * be[t];
  __syncthreads();
  acc = 0.f;
#pragma unroll 8
  for (int c = 0; c < 256; ++c) acc += bufB[c] * Wg1[c*256 + t];
  bufA[t] = fmaxf(acc * 0.0625f + bg1[t], 0.f);
  __syncthreads();
  acc = 0.f;
#pragma unroll 8
  for (int c = 0; c < 256; ++c) acc += bufA[c] * Wg2[c*256 + t];
  bufB[t] = acc + bg2[t];
  __syncthreads();
  acc = 0.f;
#pragma unroll 8
  for (int c = 0; c < 256; ++c) acc += bufB[c] * Wc1s[c*256 + t];
  bufA[t] = fmaxf(acc + bc1[t], 0.f);
  __syncthreads();
  acc = 0.f;
#pragma unroll 8
  for (int c = 0; c < 256; ++c) acc += bufA[c] * Wc2[c*256 + t];
  float h2v = fmaxf(acc + bc2[t], 0.f);

  float part = h2v * Wc3[t];
#pragma unroll
  for (int off = 1; off < 64; off <<= 1) part += __shfl_xor(part, off);
  if ((t & 63) == 0) red[t >> 6] = part;
  __syncthreads();
  if (t == 0) cval_s = tanhf(red[0] + red[1] + red[2] + red[3] + bc3[0]);
  __syncthreads();
  const float cv = cval_s;
  out[obj*256 + t] = ((t >> 4) == (t & 15)) ? 0.f : cv;
}

// ---------------------------------------------------------------------------
extern "C" void kernel_launch(void* const* d_in, const int* in_sizes, int n_in,
                              void* d_out, int out_size, void* d_ws, size_t ws_size,
                              hipStream_t stream) {
  const float* pcls = (const float*)d_in[0];
  const float* W1 = (const float*)d_in[1];  const float* b1 = (const float*)d_in[2];
  const float* g1 = (const float*)d_in[3];  const float* bt1 = (const float*)d_in[4];
  const float* W2 = (const float*)d_in[5];  const float* b2 = (const float*)d_in[6];
  const float* g2 = (const float*)d_in[7];  const float* bt2 = (const float*)d_in[8];
  const float* W3 = (const float*)d_in[9];  const float* b3 = (const float*)d_in[10];
  const float* g3 = (const float*)d_in[11]; const float* bt3 = (const float*)d_in[12];
  const float* We = (const float*)d_in[13]; const float* be = (const float*)d_in[14];
  const float* Wg1 = (const float*)d_in[15]; const float* bg1 = (const float*)d_in[16];
  const float* Wg2 = (const float*)d_in[17]; const float* bg2 = (const float*)d_in[18];
  const float* Wc1 = (const float*)d_in[19]; const float* bc1 = (const float*)d_in[20];
  const float* Wc2 = (const float*)d_in[21]; const float* bc2 = (const float*)d_in[22];
  const float* Wc3 = (const float*)d_in[23]; const float* bc3 = (const float*)d_in[24];
  unsigned char* ws = (unsigned char*)d_ws;
  float* out = (float*)d_out;

  prep_kernel<<<426, 256, 0, stream>>>(W1, b1, g1, bt1, W2, b2, g2, bt2,
                                       W3, b3, g3, bt3, Wc1, ws);
  pointnet_kernel<<<512, 256, 0, stream>>>(pcls, ws, (float*)(ws + FSUM_OFF));
  objmlp_kernel<<<512, 256, 0, stream>>>(We, be, Wg1, bg1, Wg2, bg2, bc1,
                                         Wc2, bc2, Wc3, bc3, ws, out);
}